// Round 13
// baseline (200.494 us; speedup 1.0000x reference)
//
#include <hip/hip_runtime.h>

typedef unsigned short u16;
typedef unsigned int u32;
typedef __bf16 bf16x8 __attribute__((ext_vector_type(8)));
typedef float f32x4 __attribute__((ext_vector_type(4)));
typedef u16 u16x4 __attribute__((ext_vector_type(4)));
typedef u16 u16x8 __attribute__((ext_vector_type(8)));
typedef u32 u32x4 __attribute__((ext_vector_type(4)));

#define NB 64
#define NN 512
#define NH 12
#define HD 32
#define DIM 384

static constexpr size_t QWS = (size_t)NB * NH * NN * HD;  // bf16 elems per tensor
#define LOG2E 1.4426950408889634f
#define QSCALE 0.25503486f   // (1/sqrt(32)) * log2(e)

__device__ __forceinline__ u16 f2bf(float f) {
  __bf16 b = (__bf16)f;
  union { __bf16 b; u16 u; } v; v.b = b;
  return v.u;
}
__device__ __forceinline__ float lo16f(u32 w) {
  union { u32 u; float f; } v; v.u = w << 16;
  return v.f;
}
__device__ __forceinline__ float hi16f(u32 w) {
  union { u32 u; float f; } v; v.u = w & 0xffff0000u;
  return v.f;
}

// ---------------------------------------------------------------------------
// Kernel 1 (prep): blocks [0,6144): bias -> fragment-stream beR (16x16 frags).
//   blocks [6144,6360): W -> 16x16 A-frag stream Wf bf16:
//   Wf[cb 72][kk 12][lane 64][8]: j = cb*16+(lane&15), k = kk*32+(lane>>4)*8+e.
// ---------------------------------------------------------------------------
__global__ __launch_bounds__(256) void prep_k(const float* __restrict__ table,
                                              const int* __restrict__ rel,
                                              const float* __restrict__ Wq,
                                              const float* __restrict__ Wkv,
                                              u32* __restrict__ beR,
                                              u16* __restrict__ Wf) {
  int bid = blockIdx.x;
  if (bid < 6144) {
    int t = bid * 256 + threadIdx.x;   // 1,572,864 words
    int word = t & 3;
    int lane = (t >> 2) & 63;
    int mf   = (t >> 8) & 3;
    int wv   = (t >> 10) & 7;
    int kt   = (t >> 13) & 15;
    int h    = t >> 17;
    int lr = lane & 15, lg = lane >> 4;
    int q = wv * 64 + mf * 16 + lr;
    int k = kt * 32 + (word >> 1) * 16 + lg * 4 + (word & 1) * 2;
    int i0 = rel[q * NN + k];
    int i1 = rel[q * NN + k + 1];
    u16 b0 = f2bf(table[i0 * NH + h] * LOG2E);
    u16 b1 = f2bf(table[i1 * NH + h] * LOG2E);
    beR[t] = (u32)b0 | ((u32)b1 << 16);
  } else {
    int t2 = (bid - 6144) * 256 + threadIdx.x;   // 0..55295 = (cb*12+kk)*64+lane
    int lane = t2 & 63;
    int kk = (t2 >> 6) % 12;
    int cb = t2 / (12 * 64);
    int j = cb * 16 + (lane & 15);
    int k = kk * 32 + (lane >> 4) * 8;
    const float* wrow = (j < 384) ? (Wq + (size_t)j * DIM) : (Wkv + (size_t)(j - 384) * DIM);
    float4 a = *(const float4*)(wrow + k);
    float4 b = *(const float4*)(wrow + k + 4);
    u16x8 o = {f2bf(a.x), f2bf(a.y), f2bf(a.z), f2bf(a.w),
               f2bf(b.x), f2bf(b.y), f2bf(b.z), f2bf(b.w)};
    *(u16x8*)(Wf + (size_t)t2 * 8) = o;
  }
}

// ---------------------------------------------------------------------------
// Kernel 2: QKV projection, pure streaming, ZERO LDS / ZERO barriers.
//   3072 blocks x 256 thr: type = vv/1024, m0 = (vv%1024)*32 (32 rows/block).
//   X fragments af[2][12] (96 VGPR) loaded once per block; per wave 6 colblks,
//   W fragments streamed per-colblk from the Wf stream as 12 contiguous 16B
//   dwordx4 loads (L2-resident, XCD-clustered). Each W-frag feeds 2 MFMAs
//   (row-groups). C layout D[j][n]: lane stores 4 consecutive d = 8B store.
// ---------------------------------------------------------------------------
__global__ __launch_bounds__(256, 3) void qkv_proj_k(const float* __restrict__ x1,
                                                     const float* __restrict__ x2,
                                                     const float* __restrict__ qb,
                                                     const float* __restrict__ vb,
                                                     const u16* __restrict__ Wf,
                                                     u16* __restrict__ q_ws,
                                                     u16* __restrict__ k_ws,
                                                     u16* __restrict__ v_ws) {
  const int g = blockIdx.x;                   // 0..3071
  const int vv = (g & 7) * 384 + (g >> 3);    // XCD-chunked, bijective (3072=8*384)
  const int type = vv >> 10;                  // 0:q 1:k 2:v
  const int m0 = (vv & 1023) * 32;            // row base (32 rows/block)
  const int tid = threadIdx.x, lane = tid & 63, w = tid >> 6;  // w 0..3
  const int lg = lane >> 4, lr = lane & 15;
  const float* X = (type == 0) ? x1 : x2;
  const int bb = m0 >> 9, m0r = m0 & 511;

  // X fragments: rowgroups {0,16}, rows m0 + rg*16 + lr, k = kk*32 + lg*8 + e
  bf16x8 af0[12], af1[12];
  {
    const float* xlo = X + (size_t)(m0 + lr) * DIM + lg * 8;
    const float* xhi = xlo + (size_t)16 * DIM;
#pragma unroll
    for (int kk = 0; kk < 12; ++kk) {
      float4 a = *(const float4*)(xlo + kk * 32);
      float4 b = *(const float4*)(xlo + kk * 32 + 4);
      af0[kk] = (bf16x8){(__bf16)a.x, (__bf16)a.y, (__bf16)a.z, (__bf16)a.w,
                         (__bf16)b.x, (__bf16)b.y, (__bf16)b.z, (__bf16)b.w};
      float4 c = *(const float4*)(xhi + kk * 32);
      float4 d = *(const float4*)(xhi + kk * 32 + 4);
      af1[kk] = (bf16x8){(__bf16)c.x, (__bf16)c.y, (__bf16)c.z, (__bf16)c.w,
                         (__bf16)d.x, (__bf16)d.y, (__bf16)d.z, (__bf16)d.w};
    }
  }

  u16* dst = (type == 0) ? q_ws : (type == 1 ? k_ws : v_ws);
  const float* bias = (type == 0) ? qb : (type == 2 ? vb : nullptr);
  const float scale = (type == 0) ? QSCALE : 1.0f;

  // wave w owns type-local colblks w*6 .. w*6+5
  for (int cw = 0; cw < 6; ++cw) {
    int cb = w * 6 + cw;                                   // type-local 0..23
    const u16* wc = Wf + (((size_t)(type * 24 + cb) * 12) * 64 + lane) * 8;
    bf16x8 wf[12];
#pragma unroll
    for (int kk = 0; kk < 12; ++kk)
      wf[kk] = *(const bf16x8*)(wc + (size_t)kk * 512);
    f32x4 a0 = {0.f, 0.f, 0.f, 0.f};
    f32x4 a1 = {0.f, 0.f, 0.f, 0.f};
#pragma unroll
    for (int kk = 0; kk < 12; ++kk) {
      a0 = __builtin_amdgcn_mfma_f32_16x16x32_bf16(wf[kk], af0[kk], a0, 0, 0, 0);
      a1 = __builtin_amdgcn_mfma_f32_16x16x32_bf16(wf[kk], af1[kk], a1, 0, 0, 0);
    }
    // epilogue: head = cb>>1; lane holds j = cb*16 + lg*4 + r -> d0..d0+3
    int head = cb >> 1;
    int d0 = (cb & 1) * 16 + lg * 4;
    float4 bv = {0.f, 0.f, 0.f, 0.f};
    if (type != 1) bv = *(const float4*)(bias + head * 32 + d0);
    size_t obase = ((size_t)(bb * NH + head) * NN + m0r + lr) * HD + d0;
    u16x4 o0 = {f2bf((a0[0] + bv.x) * scale), f2bf((a0[1] + bv.y) * scale),
                f2bf((a0[2] + bv.z) * scale), f2bf((a0[3] + bv.w) * scale)};
    *(u16x4*)(dst + obase) = o0;
    u16x4 o1 = {f2bf((a1[0] + bv.x) * scale), f2bf((a1[1] + bv.y) * scale),
                f2bf((a1[2] + bv.z) * scale), f2bf((a1[3] + bv.w) * scale)};
    *(u16x4*)(dst + obase + (size_t)16 * HD) = o1;
  }
}

// ---------------------------------------------------------------------------
// Kernel 3: attention (unchanged): swapped QK + k-permuted V,
// fragment-stream bias as MFMA C operand.
// ---------------------------------------------------------------------------
__global__ __launch_bounds__(512, 4) void attn_k(const u16* __restrict__ qw,
                                                 const u16* __restrict__ kw,
                                                 const u16* __restrict__ vw,
                                                 const u32* __restrict__ beR,
                                                 float* __restrict__ out) {
  const int g = blockIdx.x;                 // 0..767
  const int vv = (g & 7) * 96 + (g >> 3);   // chunk per XCD
  const int h = vv >> 6, b = vv & 63;
  const size_t base = ((size_t)b * NH + h) * NN * HD;
  const u16* Q = qw + base;
  const u16* K = kw + base;
  const u16* V = vw + base;

  __shared__ u16 Ks[NN][40];     // [k][d], 80B stride
  __shared__ u16 Vtp[HD][520];   // [d][k-permuted], 1040B stride

  const int tid = threadIdx.x;
  const int lane = tid & 63, w = tid >> 6;
  const int lg = lane >> 4, lr = lane & 15;
  const int q0 = w * 64;

  bf16x8 qf[4];
#pragma unroll
  for (int mf = 0; mf < 4; ++mf)
    qf[mf] = *(const bf16x8*)&Q[(q0 + mf * 16 + lr) * HD + lg * 8];

  for (int c = tid; c < 2048; c += 512) {
    int row = c >> 2, part = (c & 3) * 8;
    *(u16x8*)&Ks[row][part] = *(const u16x8*)&K[row * HD + part];
    u16x8 vld = *(const u16x8*)&V[row * HD + part];
    int kk = row & 31;
    int col = (row & ~31) + ((kk >> 2) & 3) * 8 + (kk >> 4) * 4 + (kk & 3);
#pragma unroll
    for (int j = 0; j < 8; ++j) Vtp[part + j][col] = vld[j];
  }
  __syncthreads();

  const u32* bstream = beR + ((((size_t)h * 16) * 8 + w) * 4) * 256 + lane * 4;

  f32x4 accOT[4][2] = {};
  float lsum[4] = {0.f, 0.f, 0.f, 0.f};

  for (int kt = 0; kt < 16; ++kt) {
    const int k0 = kt * 32;
    const u32* bkt = bstream + (size_t)kt * 8192;
    bf16x8 kf0 = *(const bf16x8*)&Ks[k0 + lr][lg * 8];
    bf16x8 kf1 = *(const bf16x8*)&Ks[k0 + 16 + lr][lg * 8];
    bf16x8 vp0 = *(const bf16x8*)&Vtp[lr][k0 + lg * 8];
    bf16x8 vp1 = *(const bf16x8*)&Vtp[16 + lr][k0 + lg * 8];
#pragma unroll
    for (int mf = 0; mf < 4; ++mf) {
      u32x4 bbv = *(const u32x4*)(bkt + mf * 256);
      f32x4 c0 = {lo16f(bbv.x), hi16f(bbv.x), lo16f(bbv.y), hi16f(bbv.y)};
      f32x4 c1 = {lo16f(bbv.z), hi16f(bbv.z), lo16f(bbv.w), hi16f(bbv.w)};
      f32x4 s0 = __builtin_amdgcn_mfma_f32_16x16x32_bf16(kf0, qf[mf], c0, 0, 0, 0);
      f32x4 s1 = __builtin_amdgcn_mfma_f32_16x16x32_bf16(kf1, qf[mf], c1, 0, 0, 0);
      float p0[4], p1[4];
#pragma unroll
      for (int r = 0; r < 4; ++r) {
        p0[r] = __builtin_amdgcn_exp2f(s0[r]);
        p1[r] = __builtin_amdgcn_exp2f(s1[r]);
      }
      lsum[mf] += ((p0[0] + p0[1]) + (p0[2] + p0[3])) +
                  ((p1[0] + p1[1]) + (p1[2] + p1[3]));
      bf16x8 pv = {(__bf16)p0[0], (__bf16)p0[1], (__bf16)p0[2], (__bf16)p0[3],
                   (__bf16)p1[0], (__bf16)p1[1], (__bf16)p1[2], (__bf16)p1[3]};
      accOT[mf][0] = __builtin_amdgcn_mfma_f32_16x16x32_bf16(vp0, pv, accOT[mf][0], 0, 0, 0);
      accOT[mf][1] = __builtin_amdgcn_mfma_f32_16x16x32_bf16(vp1, pv, accOT[mf][1], 0, 0, 0);
    }
  }

  float linv[4];
#pragma unroll
  for (int mf = 0; mf < 4; ++mf) {
    float s = lsum[mf];
    s += __shfl_xor(s, 16, 64);
    s += __shfl_xor(s, 32, 64);
    linv[mf] = 1.0f / s;
  }

  float* outp = out + ((size_t)b * NN) * DIM + h * HD;
#pragma unroll
  for (int mf = 0; mf < 4; ++mf) {
    int q = q0 + mf * 16 + lr;
#pragma unroll
    for (int nf = 0; nf < 2; ++nf) {
      float4 o = {accOT[mf][nf][0] * linv[mf], accOT[mf][nf][1] * linv[mf],
                  accOT[mf][nf][2] * linv[mf], accOT[mf][nf][3] * linv[mf]};
      *(float4*)&outp[(size_t)q * DIM + nf * 16 + lg * 4] = o;
    }
  }
}

// ---------------------------------------------------------------------------
extern "C" void kernel_launch(void* const* d_in, const int* in_sizes, int n_in,
                              void* d_out, int out_size, void* d_ws, size_t ws_size,
                              hipStream_t stream) {
  const float* x1    = (const float*)d_in[0];
  const float* x2    = (const float*)d_in[1];
  const float* Wq    = (const float*)d_in[2];
  const float* Wkv   = (const float*)d_in[3];
  const float* qb    = (const float*)d_in[4];
  const float* vb    = (const float*)d_in[5];
  const float* table = (const float*)d_in[6];
  const int*   rel   = (const int*)d_in[7];
  float* out = (float*)d_out;

  u16* ws   = (u16*)d_ws;
  u16* q_ws = ws;
  u16* k_ws = ws + QWS;
  u16* v_ws = ws + 2 * QWS;
  u32* beR  = (u32*)(ws + 3 * QWS);          // 1,572,864 u32 = 6.3 MB
  u16* Wf   = ws + 3 * QWS + 2 * 1572864;    // 442,368 u16 = 0.88 MB

  prep_k<<<6360, 256, 0, stream>>>(table, rel, Wq, Wkv, beR, Wf);
  qkv_proj_k<<<3072, 256, 0, stream>>>(x1, x2, qb, vb, Wf, q_ws, k_ws, v_ws);
  attn_k<<<NB * NH, 512, 0, stream>>>(q_ws, k_ws, v_ws, beR, out);
}

// Round 14
// 117.959 us; speedup vs baseline: 1.6997x; 1.6997x over previous
//
#include <hip/hip_runtime.h>

typedef unsigned short u16;
typedef unsigned int u32;
typedef __bf16 bf16x8 __attribute__((ext_vector_type(8)));
typedef float f32x4 __attribute__((ext_vector_type(4)));
typedef u16 u16x8 __attribute__((ext_vector_type(8)));
typedef u32 u32x4 __attribute__((ext_vector_type(4)));

#define NB 64
#define NN 512
#define NH 12
#define HD 32
#define DIM 384

static constexpr size_t QWS = (size_t)NB * NH * NN * HD;  // bf16 elems per tensor
#define LOG2E 1.4426950408889634f
#define QSCALE 0.25503486f   // (1/sqrt(32)) * log2(e)

__device__ __forceinline__ u16 f2bf(float f) {
  __bf16 b = (__bf16)f;
  union { __bf16 b; u16 u; } v; v.b = b;
  return v.u;
}
__device__ __forceinline__ float lo16f(u32 w) {
  union { u32 u; float f; } v; v.u = w << 16;
  return v.f;
}
__device__ __forceinline__ float hi16f(u32 w) {
  union { u32 u; float f; } v; v.u = w & 0xffff0000u;
  return v.f;
}
__device__ __forceinline__ void gload16(const void* g, void* l) {
  __builtin_amdgcn_global_load_lds((const __attribute__((address_space(1))) u32*)g,
                                   (__attribute__((address_space(3))) u32*)l, 16, 0, 0);
}

// ---------------------------------------------------------------------------
// Kernel 1 (wprep): W f32 -> 16x16 A-frag stream Wf bf16 (R8 layout):
//   Wf[cb 72][kk 12][lane 64][8]: j = cb*16+(lane&15), k = kk*32+(lane>>4)*8+e.
// ---------------------------------------------------------------------------
__global__ __launch_bounds__(256) void wprep_k(const float* __restrict__ Wq,
                                               const float* __restrict__ Wkv,
                                               u16* __restrict__ Wf) {
  int t2 = blockIdx.x * 256 + threadIdx.x;   // 0..55295 = (cb*12+kk)*64+lane
  int lane = t2 & 63;
  int kk = (t2 >> 6) % 12;
  int cb = t2 / (12 * 64);
  int j = cb * 16 + (lane & 15);
  int k = kk * 32 + (lane >> 4) * 8;
  const float* wrow = (j < 384) ? (Wq + (size_t)j * DIM) : (Wkv + (size_t)(j - 384) * DIM);
  float4 a = *(const float4*)(wrow + k);
  float4 b = *(const float4*)(wrow + k + 4);
  u16x8 o = {f2bf(a.x), f2bf(a.y), f2bf(a.z), f2bf(a.w),
             f2bf(b.x), f2bf(b.y), f2bf(b.z), f2bf(b.w)};
  *(u16x8*)(Wf + (size_t)t2 * 8) = o;
}

// ---------------------------------------------------------------------------
// Kernel 2 (merged): blocks [0,768): QKV projection (R8 structure, balanced:
//   type = vv>>8 in {q, kv-low, kv-high}, every block 128 rows x 24 cols =
//   12 chunks of 24KB W via global_load_lds dbuf; 8 waves x 16 rows so the
//   remat'd X slice is L1-resident). blocks [768,3840): bias-expand into the
//   fragment-stream beR — fills the 4th block slot per CU during proj.
// ---------------------------------------------------------------------------
__global__ __launch_bounds__(512, 4) void proj_bias_k(const float* __restrict__ x1,
                                                      const float* __restrict__ x2,
                                                      const float* __restrict__ qb,
                                                      const float* __restrict__ vb,
                                                      const u16* __restrict__ Wf,
                                                      const float* __restrict__ table,
                                                      const int* __restrict__ rel,
                                                      u32* __restrict__ beR,
                                                      u16* __restrict__ q_ws,
                                                      u16* __restrict__ k_ws,
                                                      u16* __restrict__ v_ws) {
  __shared__ __attribute__((aligned(16))) u16 Wbuf[2][12288];  // 2 x 24KB

  const int bid = blockIdx.x;
  const int tid = threadIdx.x;

  if (bid >= 768) {
    // ---- bias-expand: fragment-stream beR (same mapping as before) ----
    int t = (bid - 768) * 512 + tid;   // 0..1,572,863 words
    int word = t & 3;
    int lane2 = (t >> 2) & 63;
    int mf   = (t >> 8) & 3;
    int wv   = (t >> 10) & 7;
    int kt   = (t >> 13) & 15;
    int h    = t >> 17;
    int lr2 = lane2 & 15, lg2 = lane2 >> 4;
    int q = wv * 64 + mf * 16 + lr2;
    int k = kt * 32 + (word >> 1) * 16 + lg2 * 4 + (word & 1) * 2;
    int i0 = rel[q * NN + k];
    int i1 = rel[q * NN + k + 1];
    u16 b0 = f2bf(table[i0 * NH + h] * LOG2E);
    u16 b1 = f2bf(table[i1 * NH + h] * LOG2E);
    beR[t] = (u32)b0 | ((u32)b1 << 16);
    return;
  }

  // ---- QKV projection, balanced R8 structure ----
  const int vv = (bid & 7) * 96 + (bid >> 3);  // XCD-chunked, bijective over 768
  const int t3 = vv >> 8;                      // 0: q cols, 1: kv-low, 2: kv-high
  const int m0 = (vv & 255) * 128;
  const int cb0 = t3 * 24;                     // global colblk base
  const int lane = tid & 63, w = tid >> 6;
  const int lg = lane >> 4, lr = lane & 15;
  const float* X = (t3 == 0) ? x1 : x2;
  const int is_q = (t3 == 0);
  const char* wsrc = (const char*)(Wf + (size_t)cb0 * 6144);
  const int bb = m0 >> 9, m0r = m0 & 511;

  // A fragments: rows m0 + w*16 + lr, all K (wave slice 24KB -> L1-resident)
  bf16x8 af[12];
  const float* xrow = X + (size_t)(m0 + w * 16 + lr) * DIM + lg * 8;
#pragma unroll
  for (int kk = 0; kk < 12; ++kk) {
    float4 a = *(const float4*)(xrow + kk * 32);
    float4 b = *(const float4*)(xrow + kk * 32 + 4);
    af[kk] = (bf16x8){(__bf16)a.x, (__bf16)a.y, (__bf16)a.z, (__bf16)a.w,
                      (__bf16)b.x, (__bf16)b.y, (__bf16)b.z, (__bf16)b.w};
  }

  // stage chunk 0 (24KB: 24 insts x 64 lanes x 16B)
#pragma unroll
  for (int i = 0; i < 3; ++i) {
    int inst = w + i * 8;
    gload16(wsrc + inst * 1024 + lane * 16, (char*)&Wbuf[0][0] + inst * 1024 + lane * 16);
  }
  __syncthreads();

  const float scale = is_q ? QSCALE : 1.0f;
  const int rowb = m0r + w * 16 + lg * 4;

  for (int c = 0; c < 12; ++c) {
    if (c + 1 < 12) {
      const char* s = wsrc + (size_t)(c + 1) * 24576;
      char* d = (char*)&Wbuf[(c + 1) & 1][0];
#pragma unroll
      for (int i = 0; i < 3; ++i) {
        int inst = w + i * 8;
        gload16(s + inst * 1024 + lane * 16, d + inst * 1024 + lane * 16);
      }
    }
    const u16* wb = &Wbuf[c & 1][0];
#pragma unroll
    for (int lc = 0; lc < 2; ++lc) {
      f32x4 acc = {0.f, 0.f, 0.f, 0.f};
#pragma unroll
      for (int kk = 0; kk < 12; ++kk) {
        bf16x8 wf = *(const bf16x8*)(wb + ((lc * 12 + kk) * 64 + lane) * 8);
        acc = __builtin_amdgcn_mfma_f32_16x16x32_bf16(af[kk], wf, acc, 0, 0, 0);
      }
      // epilogue: global colblk cb0 + 2c + lc
      int j = (cb0 + c * 2 + lc) * 16 + lr;          // 0..1151
      int jj = is_q ? j : (j < 768 ? j - 384 : j - 768);
      float bv = is_q ? qb[jj] : (j >= 768 ? vb[jj] : 0.0f);
      u16* dstp = is_q ? q_ws : (j < 768 ? k_ws : v_ws);
      int hh = jj >> 5, dd = jj & 31;
      size_t basead = ((size_t)(bb * NH + hh) * NN) * HD + dd;
#pragma unroll
      for (int r = 0; r < 4; ++r)
        dstp[basead + (size_t)(rowb + r) * HD] = f2bf((acc[r] + bv) * scale);
    }
    __syncthreads();
  }
}

// ---------------------------------------------------------------------------
// Kernel 3: attention (unchanged): swapped QK + k-permuted V,
// fragment-stream bias as MFMA C operand.
// ---------------------------------------------------------------------------
__global__ __launch_bounds__(512, 4) void attn_k(const u16* __restrict__ qw,
                                                 const u16* __restrict__ kw,
                                                 const u16* __restrict__ vw,
                                                 const u32* __restrict__ beR,
                                                 float* __restrict__ out) {
  const int g = blockIdx.x;                 // 0..767
  const int vv = (g & 7) * 96 + (g >> 3);   // chunk per XCD
  const int h = vv >> 6, b = vv & 63;
  const size_t base = ((size_t)b * NH + h) * NN * HD;
  const u16* Q = qw + base;
  const u16* K = kw + base;
  const u16* V = vw + base;

  __shared__ u16 Ks[NN][40];     // [k][d], 80B stride
  __shared__ u16 Vtp[HD][520];   // [d][k-permuted], 1040B stride

  const int tid = threadIdx.x;
  const int lane = tid & 63, w = tid >> 6;
  const int lg = lane >> 4, lr = lane & 15;
  const int q0 = w * 64;

  bf16x8 qf[4];
#pragma unroll
  for (int mf = 0; mf < 4; ++mf)
    qf[mf] = *(const bf16x8*)&Q[(q0 + mf * 16 + lr) * HD + lg * 8];

  for (int c = tid; c < 2048; c += 512) {
    int row = c >> 2, part = (c & 3) * 8;
    *(u16x8*)&Ks[row][part] = *(const u16x8*)&K[row * HD + part];
    u16x8 vld = *(const u16x8*)&V[row * HD + part];
    int kk = row & 31;
    int col = (row & ~31) + ((kk >> 2) & 3) * 8 + (kk >> 4) * 4 + (kk & 3);
#pragma unroll
    for (int j = 0; j < 8; ++j) Vtp[part + j][col] = vld[j];
  }
  __syncthreads();

  const u32* bstream = beR + ((((size_t)h * 16) * 8 + w) * 4) * 256 + lane * 4;

  f32x4 accOT[4][2] = {};
  float lsum[4] = {0.f, 0.f, 0.f, 0.f};

  for (int kt = 0; kt < 16; ++kt) {
    const int k0 = kt * 32;
    const u32* bkt = bstream + (size_t)kt * 8192;
    bf16x8 kf0 = *(const bf16x8*)&Ks[k0 + lr][lg * 8];
    bf16x8 kf1 = *(const bf16x8*)&Ks[k0 + 16 + lr][lg * 8];
    bf16x8 vp0 = *(const bf16x8*)&Vtp[lr][k0 + lg * 8];
    bf16x8 vp1 = *(const bf16x8*)&Vtp[16 + lr][k0 + lg * 8];
#pragma unroll
    for (int mf = 0; mf < 4; ++mf) {
      u32x4 bbv = *(const u32x4*)(bkt + mf * 256);
      f32x4 c0 = {lo16f(bbv.x), hi16f(bbv.x), lo16f(bbv.y), hi16f(bbv.y)};
      f32x4 c1 = {lo16f(bbv.z), hi16f(bbv.z), lo16f(bbv.w), hi16f(bbv.w)};
      f32x4 s0 = __builtin_amdgcn_mfma_f32_16x16x32_bf16(kf0, qf[mf], c0, 0, 0, 0);
      f32x4 s1 = __builtin_amdgcn_mfma_f32_16x16x32_bf16(kf1, qf[mf], c1, 0, 0, 0);
      float p0[4], p1[4];
#pragma unroll
      for (int r = 0; r < 4; ++r) {
        p0[r] = __builtin_amdgcn_exp2f(s0[r]);
        p1[r] = __builtin_amdgcn_exp2f(s1[r]);
      }
      lsum[mf] += ((p0[0] + p0[1]) + (p0[2] + p0[3])) +
                  ((p1[0] + p1[1]) + (p1[2] + p1[3]));
      bf16x8 pv = {(__bf16)p0[0], (__bf16)p0[1], (__bf16)p0[2], (__bf16)p0[3],
                   (__bf16)p1[0], (__bf16)p1[1], (__bf16)p1[2], (__bf16)p1[3]};
      accOT[mf][0] = __builtin_amdgcn_mfma_f32_16x16x32_bf16(vp0, pv, accOT[mf][0], 0, 0, 0);
      accOT[mf][1] = __builtin_amdgcn_mfma_f32_16x16x32_bf16(vp1, pv, accOT[mf][1], 0, 0, 0);
    }
  }

  float linv[4];
#pragma unroll
  for (int mf = 0; mf < 4; ++mf) {
    float s = lsum[mf];
    s += __shfl_xor(s, 16, 64);
    s += __shfl_xor(s, 32, 64);
    linv[mf] = 1.0f / s;
  }

  float* outp = out + ((size_t)b * NN) * DIM + h * HD;
#pragma unroll
  for (int mf = 0; mf < 4; ++mf) {
    int q = q0 + mf * 16 + lr;
#pragma unroll
    for (int nf = 0; nf < 2; ++nf) {
      float4 o = {accOT[mf][nf][0] * linv[mf], accOT[mf][nf][1] * linv[mf],
                  accOT[mf][nf][2] * linv[mf], accOT[mf][nf][3] * linv[mf]};
      *(float4*)&outp[(size_t)q * DIM + nf * 16 + lg * 4] = o;
    }
  }
}

// ---------------------------------------------------------------------------
extern "C" void kernel_launch(void* const* d_in, const int* in_sizes, int n_in,
                              void* d_out, int out_size, void* d_ws, size_t ws_size,
                              hipStream_t stream) {
  const float* x1    = (const float*)d_in[0];
  const float* x2    = (const float*)d_in[1];
  const float* Wq    = (const float*)d_in[2];
  const float* Wkv   = (const float*)d_in[3];
  const float* qb    = (const float*)d_in[4];
  const float* vb    = (const float*)d_in[5];
  const float* table = (const float*)d_in[6];
  const int*   rel   = (const int*)d_in[7];
  float* out = (float*)d_out;

  u16* ws   = (u16*)d_ws;
  u16* q_ws = ws;
  u16* k_ws = ws + QWS;
  u16* v_ws = ws + 2 * QWS;
  u32* beR  = (u32*)(ws + 3 * QWS);          // 1,572,864 u32 = 6.3 MB
  u16* Wf   = ws + 3 * QWS + 2 * 1572864;    // 442,368 u16 = 0.88 MB

  wprep_k<<<216, 256, 0, stream>>>(Wq, Wkv, Wf);
  proj_bias_k<<<3840, 512, 0, stream>>>(x1, x2, qb, vb, Wf, table, rel, beR,
                                        q_ws, k_ws, v_ws);
  attn_k<<<NB * NH, 512, 0, stream>>>(q_ws, k_ws, v_ws, beR, out);
}